// Round 1
// baseline (39938.879 us; speedup 1.0000x reference)
//
#include <hip/hip_runtime.h>
#include <math.h>

#define BATCH 128
#define HID 512
#define FEAT 128
#define SEQL 512
#define PREDL 128
#define LDSP 17   // padded LDS leading stride (conflict-free, odd)

__device__ __forceinline__ float sigf_(float x) {
  return 1.0f / (1.0f + __expf(-x));
}
__device__ __forceinline__ float tanh_(float x) {
  float ax = fabsf(x);
  float e2 = __expf(-2.0f * ax);
  float t = (1.0f - e2) / (1.0f + e2);
  return copysignf(t, x);
}

// ---------------------------------------------------------------------------
// Generic LSTM cell tile: gates = b1 + b2 (+b3) + A@WA^T + Hin@WH^T, K=512 both.
// wg in [0,256): unit-tile ut (32 tiles of 16 units), batch-tile bt (8 tiles of 16).
// XCD-affine: wg&7 picks unit group so each XCD re-reads only 1/8 of weights.
// ---------------------------------------------------------------------------
template <bool HAS_B3>
__device__ __forceinline__ void cell_core(
    int wg,
    const float* __restrict__ A, const float* __restrict__ WA,
    const float* __restrict__ Hin, const float* __restrict__ WH,
    const float* __restrict__ b1, const float* __restrict__ b2,
    const float* __restrict__ b3,
    float* __restrict__ C, float* __restrict__ Hout,
    float* __restrict__ a_s, float* __restrict__ h_s) {
  const int tid = threadIdx.x;
  const int ut = (wg & 7) * 4 + ((wg >> 3) & 3);  // 0..31
  const int bt = wg >> 5;                          // 0..7
  const int b0 = bt * 16;

  for (int idx = tid; idx < 16 * HID; idx += 256) {
    const int k = idx & (HID - 1);
    const int bb = idx >> 9;
    a_s[k * LDSP + bb] = A[(size_t)(b0 + bb) * HID + k];
    h_s[k * LDSP + bb] = Hin[(size_t)(b0 + bb) * HID + k];
  }
  __syncthreads();

  const int u = tid >> 4, b = tid & 15;
  const int ug = ut * 16 + u;

  float acc0 = b1[ug] + b2[ug];
  float acc1 = b1[512 + ug] + b2[512 + ug];
  float acc2 = b1[1024 + ug] + b2[1024 + ug];
  float acc3 = b1[1536 + ug] + b2[1536 + ug];
  if (HAS_B3) {
    acc0 += b3[ug]; acc1 += b3[512 + ug];
    acc2 += b3[1024 + ug]; acc3 += b3[1536 + ug];
  }

  const float4* __restrict__ wa0 = (const float4*)(WA + (size_t)ug * HID);
  const float4* __restrict__ wa1 = (const float4*)(WA + (size_t)(512 + ug) * HID);
  const float4* __restrict__ wa2 = (const float4*)(WA + (size_t)(1024 + ug) * HID);
  const float4* __restrict__ wa3 = (const float4*)(WA + (size_t)(1536 + ug) * HID);
  const float4* __restrict__ wh0 = (const float4*)(WH + (size_t)ug * HID);
  const float4* __restrict__ wh1 = (const float4*)(WH + (size_t)(512 + ug) * HID);
  const float4* __restrict__ wh2 = (const float4*)(WH + (size_t)(1024 + ug) * HID);
  const float4* __restrict__ wh3 = (const float4*)(WH + (size_t)(1536 + ug) * HID);

#pragma unroll 2
  for (int k4 = 0; k4 < HID / 4; ++k4) {
    const int k = k4 * 4;
    const float a0 = a_s[k * LDSP + b];
    const float a1 = a_s[(k + 1) * LDSP + b];
    const float a2 = a_s[(k + 2) * LDSP + b];
    const float a3 = a_s[(k + 3) * LDSP + b];
    const float h0 = h_s[k * LDSP + b];
    const float h1 = h_s[(k + 1) * LDSP + b];
    const float h2 = h_s[(k + 2) * LDSP + b];
    const float h3 = h_s[(k + 3) * LDSP + b];
    float4 w;
    w = wa0[k4]; acc0 += w.x * a0 + w.y * a1 + w.z * a2 + w.w * a3;
    w = wa1[k4]; acc1 += w.x * a0 + w.y * a1 + w.z * a2 + w.w * a3;
    w = wa2[k4]; acc2 += w.x * a0 + w.y * a1 + w.z * a2 + w.w * a3;
    w = wa3[k4]; acc3 += w.x * a0 + w.y * a1 + w.z * a2 + w.w * a3;
    w = wh0[k4]; acc0 += w.x * h0 + w.y * h1 + w.z * h2 + w.w * h3;
    w = wh1[k4]; acc1 += w.x * h0 + w.y * h1 + w.z * h2 + w.w * h3;
    w = wh2[k4]; acc2 += w.x * h0 + w.y * h1 + w.z * h2 + w.w * h3;
    w = wh3[k4]; acc3 += w.x * h0 + w.y * h1 + w.z * h2 + w.w * h3;
  }

  const size_t ci = (size_t)(b0 + b) * HID + ug;
  const float ig = sigf_(acc0), fg = sigf_(acc1);
  const float gg = tanh_(acc2), og = sigf_(acc3);
  const float cn = fg * C[ci] + ig * gg;
  C[ci] = cn;
  Hout[ci] = og * tanh_(cn);
}

// ---------------------------------------------------------------------------
// Teacher-forced LSTM0 step: computes e = x_t@enc_w^T+enc_b in-kernel, then
// gates = bih0+bhh0 + e@wih0^T (K=128) + Hin@whh0^T (K=512).
// ---------------------------------------------------------------------------
__device__ __forceinline__ void step0_core(
    int wg, const float* __restrict__ x, int t,
    const float* __restrict__ enc_w, const float* __restrict__ enc_b,
    const float* __restrict__ wih0, const float* __restrict__ whh0,
    const float* __restrict__ bih0, const float* __restrict__ bhh0,
    const float* __restrict__ Hin, float* __restrict__ C,
    float* __restrict__ Hout,
    float* __restrict__ xe_s, float* __restrict__ h_s) {
  const int tid = threadIdx.x;
  const int ut = (wg & 7) * 4 + ((wg >> 3) & 3);
  const int bt = wg >> 5;
  const int b0 = bt * 16;
  float* x_s = xe_s;                 // [128][LDSP]
  float* e_s = xe_s + FEAT * LDSP;   // [128][LDSP]

  for (int idx = tid; idx < 16 * HID; idx += 256) {
    const int k = idx & (HID - 1);
    const int bb = idx >> 9;
    h_s[k * LDSP + bb] = Hin[(size_t)(b0 + bb) * HID + k];
  }
  for (int idx = tid; idx < 16 * FEAT; idx += 256) {
    const int k = idx & (FEAT - 1);
    const int bb = idx >> 7;
    x_s[k * LDSP + bb] = x[((size_t)(b0 + bb) * SEQL + t) * FEAT + k];
  }
  __syncthreads();

  {  // encoder tile: 16 batches x 128 outputs
    const int b = tid & 15, jg = tid >> 4;
#pragma unroll
    for (int jj = 0; jj < 8; ++jj) {
      const int j = jg * 8 + jj;
      float acc = enc_b[j];
      const float4* __restrict__ wr = (const float4*)(enc_w + (size_t)j * FEAT);
#pragma unroll 4
      for (int k4 = 0; k4 < FEAT / 4; ++k4) {
        const float4 w = wr[k4];
        const int k = k4 * 4;
        acc += w.x * x_s[k * LDSP + b] + w.y * x_s[(k + 1) * LDSP + b] +
               w.z * x_s[(k + 2) * LDSP + b] + w.w * x_s[(k + 3) * LDSP + b];
      }
      e_s[j * LDSP + b] = acc;
    }
  }
  __syncthreads();

  const int u = tid >> 4, b = tid & 15;
  const int ug = ut * 16 + u;
  float acc0 = bih0[ug] + bhh0[ug];
  float acc1 = bih0[512 + ug] + bhh0[512 + ug];
  float acc2 = bih0[1024 + ug] + bhh0[1024 + ug];
  float acc3 = bih0[1536 + ug] + bhh0[1536 + ug];

  const float4* __restrict__ wh0 = (const float4*)(whh0 + (size_t)ug * HID);
  const float4* __restrict__ wh1 = (const float4*)(whh0 + (size_t)(512 + ug) * HID);
  const float4* __restrict__ wh2 = (const float4*)(whh0 + (size_t)(1024 + ug) * HID);
  const float4* __restrict__ wh3 = (const float4*)(whh0 + (size_t)(1536 + ug) * HID);
#pragma unroll 2
  for (int k4 = 0; k4 < HID / 4; ++k4) {
    const int k = k4 * 4;
    const float h0 = h_s[k * LDSP + b];
    const float h1 = h_s[(k + 1) * LDSP + b];
    const float h2 = h_s[(k + 2) * LDSP + b];
    const float h3 = h_s[(k + 3) * LDSP + b];
    float4 w;
    w = wh0[k4]; acc0 += w.x * h0 + w.y * h1 + w.z * h2 + w.w * h3;
    w = wh1[k4]; acc1 += w.x * h0 + w.y * h1 + w.z * h2 + w.w * h3;
    w = wh2[k4]; acc2 += w.x * h0 + w.y * h1 + w.z * h2 + w.w * h3;
    w = wh3[k4]; acc3 += w.x * h0 + w.y * h1 + w.z * h2 + w.w * h3;
  }
  const float4* __restrict__ wi0 = (const float4*)(wih0 + (size_t)ug * FEAT);
  const float4* __restrict__ wi1 = (const float4*)(wih0 + (size_t)(512 + ug) * FEAT);
  const float4* __restrict__ wi2 = (const float4*)(wih0 + (size_t)(1024 + ug) * FEAT);
  const float4* __restrict__ wi3 = (const float4*)(wih0 + (size_t)(1536 + ug) * FEAT);
#pragma unroll 2
  for (int k4 = 0; k4 < FEAT / 4; ++k4) {
    const int k = k4 * 4;
    const float e0 = e_s[k * LDSP + b];
    const float e1 = e_s[(k + 1) * LDSP + b];
    const float e2 = e_s[(k + 2) * LDSP + b];
    const float e3 = e_s[(k + 3) * LDSP + b];
    float4 w;
    w = wi0[k4]; acc0 += w.x * e0 + w.y * e1 + w.z * e2 + w.w * e3;
    w = wi1[k4]; acc1 += w.x * e0 + w.y * e1 + w.z * e2 + w.w * e3;
    w = wi2[k4]; acc2 += w.x * e0 + w.y * e1 + w.z * e2 + w.w * e3;
    w = wi3[k4]; acc3 += w.x * e0 + w.y * e1 + w.z * e2 + w.w * e3;
  }

  const size_t ci = (size_t)(b0 + b) * HID + ug;
  const float ig = sigf_(acc0), fg = sigf_(acc1);
  const float gg = tanh_(acc2), og = sigf_(acc3);
  const float cn = fg * C[ci] + ig * gg;
  C[ci] = cn;
  Hout[ci] = og * tanh_(cn);
}

// ---------------------------------------------------------------------------
// Decoder tile: out[b, step, :] = h1 @ dec_w^T + dec_b.  wg in [0,64).
// ---------------------------------------------------------------------------
__device__ __forceinline__ void dec_core(
    int wg, const float* __restrict__ h1, const float* __restrict__ dec_w,
    const float* __restrict__ dec_b, float* __restrict__ out, int step,
    float* __restrict__ h_s) {
  const int tid = threadIdx.x;
  const int jt = wg & 7, bt = wg >> 3, b0 = bt * 16;
  for (int idx = tid; idx < 16 * HID; idx += 256) {
    const int k = idx & (HID - 1);
    const int bb = idx >> 9;
    h_s[k * LDSP + bb] = h1[(size_t)(b0 + bb) * HID + k];
  }
  __syncthreads();
  const int jl = tid & 15, b = tid >> 4;
  const int j = jt * 16 + jl;
  float acc = dec_b[j];
  const float4* __restrict__ wr = (const float4*)(dec_w + (size_t)j * HID);
#pragma unroll 2
  for (int k4 = 0; k4 < HID / 4; ++k4) {
    const float4 w = wr[k4];
    const int k = k4 * 4;
    acc += w.x * h_s[k * LDSP + b] + w.y * h_s[(k + 1) * LDSP + b] +
           w.z * h_s[(k + 2) * LDSP + b] + w.w * h_s[(k + 3) * LDSP + b];
  }
  out[((size_t)(b0 + b) * PREDL + step) * FEAT + j] = acc;
}

// ---------------------------------------------------------------------------
// Kernels
// ---------------------------------------------------------------------------

// Teacher tick t: WGs 0..255 do LSTM0(t) (with in-kernel encoder);
// WGs 256..511 do LSTM1(t-1) (independent -> one kernel per step).
__global__ __launch_bounds__(256, 2) void k_tick_tf(
    const float* __restrict__ x,
    const float* __restrict__ enc_w, const float* __restrict__ enc_b,
    const float* __restrict__ wih0, const float* __restrict__ whh0,
    const float* __restrict__ bih0, const float* __restrict__ bhh0,
    const float* __restrict__ wih1, const float* __restrict__ whh1,
    const float* __restrict__ bih1, const float* __restrict__ bhh1,
    const float* __restrict__ h0in, float* __restrict__ c0,
    float* __restrict__ h0out,
    const float* __restrict__ h1in, float* __restrict__ c1,
    float* __restrict__ h1out, int t) {
  __shared__ float s1[HID * LDSP];
  __shared__ float s2[HID * LDSP];
  const int wg = blockIdx.x;
  if (wg < 256) {
    step0_core(wg, x, t, enc_w, enc_b, wih0, whh0, bih0, bhh0,
               h0in, c0, h0out, s1, s2);
  } else if (t > 0) {
    // LSTM1 at step t-1: A = h0 after (t-1) == h0in buffer
    cell_core<false>(wg - 256, h0in, wih1, h1in, whh1, bih1, bhh1, nullptr,
                     c1, h1out, s1, s2);
  }
}

// Generic standalone cell (LSTM1 steps)
__global__ __launch_bounds__(256, 2) void k_cell(
    const float* __restrict__ A, const float* __restrict__ WA,
    const float* __restrict__ Hin, const float* __restrict__ WH,
    const float* __restrict__ b1, const float* __restrict__ b2,
    float* __restrict__ C, float* __restrict__ Hout) {
  __shared__ float s1[HID * LDSP];
  __shared__ float s2[HID * LDSP];
  cell_core<false>(blockIdx.x, A, WA, Hin, WH, b1, b2, nullptr, C, Hout, s1, s2);
}

// Autoregressive LSTM0 via composite Wcomp (+ off-path decoder of h1(t-1))
__global__ __launch_bounds__(256, 2) void k_ar_a(
    const float* __restrict__ h1prev, const float* __restrict__ Wcomp,
    const float* __restrict__ h0in, const float* __restrict__ whh0,
    const float* __restrict__ bih0, const float* __restrict__ bhh0,
    const float* __restrict__ bcomp, float* __restrict__ c0,
    float* __restrict__ h0out,
    const float* __restrict__ dec_w, const float* __restrict__ dec_b,
    float* __restrict__ out, int step) {
  __shared__ float s1[HID * LDSP];
  __shared__ float s2[HID * LDSP];
  const int wg = blockIdx.x;
  if (wg < 256) {
    cell_core<true>(wg, h1prev, Wcomp, h0in, whh0, bih0, bhh0, bcomp,
                    c0, h0out, s1, s2);
  } else {
    dec_core(wg - 256, h1prev, dec_w, dec_b, out, step, s2);
  }
}

__global__ __launch_bounds__(256, 2) void k_dec(
    const float* __restrict__ h1, const float* __restrict__ dec_w,
    const float* __restrict__ dec_b, float* __restrict__ out, int step) {
  __shared__ float s2[HID * LDSP];
  dec_core(blockIdx.x, h1, dec_w, dec_b, out, step, s2);
}

// ----- prologue: composite weight/bias ------------------------------------
// B1[j][m] = sum_k enc_w[j,k] * dec_w[k,m]    (128x512, K=128)
__global__ void k_b1(const float* __restrict__ enc_w,
                     const float* __restrict__ dec_w, float* __restrict__ B1) {
  const int idx = blockIdx.x * 256 + threadIdx.x;
  const int j = idx >> 9, m = idx & 511;
  float acc = 0.0f;
  for (int k = 0; k < FEAT; ++k) acc += enc_w[j * FEAT + k] * dec_w[k * HID + m];
  B1[idx] = acc;
}
// Wcomp[n][m] = sum_j wih0[n,j] * B1[j,m]     (2048x512, K=128)
__global__ void k_wcomp(const float* __restrict__ wih0,
                        const float* __restrict__ B1, float* __restrict__ W) {
  const size_t idx = (size_t)blockIdx.x * 256 + threadIdx.x;
  const int n = (int)(idx >> 9), m = (int)(idx & 511);
  float acc = 0.0f;
  for (int k = 0; k < FEAT; ++k) acc += wih0[n * FEAT + k] * B1[k * HID + m];
  W[idx] = acc;
}
// te[j] = enc_b[j] + sum_k dec_b[k] * enc_w[j,k]
__global__ void k_te(const float* __restrict__ enc_w,
                     const float* __restrict__ enc_b,
                     const float* __restrict__ dec_b, float* __restrict__ te) {
  const int j = threadIdx.x;
  float acc = enc_b[j];
  for (int k = 0; k < FEAT; ++k) acc += dec_b[k] * enc_w[j * FEAT + k];
  te[j] = acc;
}
// bcomp[n] = sum_j wih0[n,j] * te[j]
__global__ void k_bcomp(const float* __restrict__ wih0,
                        const float* __restrict__ te, float* __restrict__ bc) {
  const int n = blockIdx.x * 256 + threadIdx.x;
  float acc = 0.0f;
  for (int j = 0; j < FEAT; ++j) acc += wih0[n * FEAT + j] * te[j];
  bc[n] = acc;
}

// ---------------------------------------------------------------------------
extern "C" void kernel_launch(void* const* d_in, const int* in_sizes, int n_in,
                              void* d_out, int out_size, void* d_ws,
                              size_t ws_size, hipStream_t stream) {
  const float* x     = (const float*)d_in[0];
  const float* enc_w = (const float*)d_in[1];
  const float* enc_b = (const float*)d_in[2];
  const float* dec_w = (const float*)d_in[3];
  const float* dec_b = (const float*)d_in[4];
  const float* wih0  = (const float*)d_in[5];
  const float* whh0  = (const float*)d_in[6];
  const float* bih0  = (const float*)d_in[7];
  const float* bhh0  = (const float*)d_in[8];
  const float* wih1  = (const float*)d_in[9];
  const float* whh1  = (const float*)d_in[10];
  const float* bih1  = (const float*)d_in[11];
  const float* bhh1  = (const float*)d_in[12];
  float* out = (float*)d_out;

  float* ws = (float*)d_ws;
  float* Wcomp = ws;                    // 2048*512 = 1048576
  float* B1    = ws + 1048576;          // 128*512  = 65536
  float* te    = ws + 1114112;          // 128
  float* bcomp = ws + 1114240;          // 2048
  float* h0b0  = ws + 1116288;          // 6 x 65536 state arrays, contiguous
  float* h0b[2] = { h0b0, h0b0 + 65536 };
  float* h1b[2] = { h0b0 + 2 * 65536, h0b0 + 3 * 65536 };
  float* c0 = h0b0 + 4 * 65536;
  float* c1 = h0b0 + 5 * 65536;

  // zero all states (h0 x2, h1 x2, c0, c1)
  hipMemsetAsync(h0b0, 0, (size_t)6 * 65536 * sizeof(float), stream);

  k_b1<<<256, 256, 0, stream>>>(enc_w, dec_w, B1);
  k_wcomp<<<4096, 256, 0, stream>>>(wih0, B1, Wcomp);
  k_te<<<1, 128, 0, stream>>>(enc_w, enc_b, dec_b, te);
  k_bcomp<<<8, 256, 0, stream>>>(wih0, te, bcomp);

  // Teacher-forced phase: tick t computes LSTM0(t) and LSTM1(t-1)
  for (int t = 0; t < SEQL; ++t) {
    k_tick_tf<<<512, 256, 0, stream>>>(
        x, enc_w, enc_b, wih0, whh0, bih0, bhh0, wih1, whh1, bih1, bhh1,
        h0b[(t + 1) & 1], c0, h0b[t & 1],
        h1b[t & 1], c1, h1b[(t + 1) & 1], t);
  }
  // LSTM1(511): A = h0 after 511 (h0b[1]), Hin = h1 after 510 (h1b[0])
  k_cell<<<256, 256, 0, stream>>>(h0b[1], wih1, h1b[0], whh1, bih1, bhh1,
                                  c1, h1b[1]);

  // Autoregressive phase: gates0(t) = h1(t-1)@Wcomp^T + bcomp + h0(t-1)@whh0^T
  for (int t = SEQL; t < SEQL + PREDL - 1; ++t) {
    k_ar_a<<<320, 256, 0, stream>>>(
        h1b[(t + 1) & 1], Wcomp, h0b[(t + 1) & 1], whh0, bih0, bhh0, bcomp,
        c0, h0b[t & 1], dec_w, dec_b, out, t - SEQL);
    k_cell<<<256, 256, 0, stream>>>(h0b[t & 1], wih1, h1b[(t + 1) & 1], whh1,
                                    bih1, bhh1, c1, h1b[t & 1]);
  }
  // final output: decode h1(638) (parity 638&1 == 0)
  k_dec<<<64, 256, 0, stream>>>(h1b[0], dec_w, dec_b, out, PREDL - 1);
}